// Round 15
// baseline (234.296 us; speedup 1.0000x reference)
//
#include <hip/hip_runtime.h>
#include <hip/hip_bf16.h>

typedef unsigned short u16;
typedef __attribute__((ext_vector_type(8))) short short8;
typedef __attribute__((ext_vector_type(4))) float f32x4;
typedef __attribute__((ext_vector_type(16))) float f32x16;
typedef __attribute__((ext_vector_type(2))) unsigned int u32x2;

#define MODEL 768
// 1/sqrt(128) * log2(e): exp(s/sqrt(128)) == exp2(s * SCALE2)
#define SCALE2 0.1275174137f

__device__ __forceinline__ float bf2f(u16 u) {
  unsigned int x = ((unsigned int)u) << 16;
  return __uint_as_float(x);
}
__device__ __forceinline__ u16 f2bf(float f) {
  unsigned int x = __float_as_uint(f);
  unsigned int r = (x + 0x7FFFu + ((x >> 16) & 1u)) >> 16;
  return (u16)r;
}
__device__ __forceinline__ void lds_ld16(const u16* g, u16* l) {
  __builtin_amdgcn_global_load_lds((const __attribute__((address_space(1))) void*)g,
                                   (__attribute__((address_space(3))) void*)l, 16, 0, 0);
}
__device__ __forceinline__ unsigned int cvtpk_bf16(float lo, float hi_) {
  unsigned int r;
  asm("v_cvt_pk_bf16_f32 %0, %1, %2" : "=v"(r) : "v"(lo), "v"(hi_));
  return r;
}

// ---------------------------------------------------------------------------
// Kernel 1 (prep): convert Wq,Wk,Wv,Wo f32->bf16 AND zero accO/accL.
// ---------------------------------------------------------------------------
__global__ __launch_bounds__(256) void r15_prep(const float* __restrict__ wq,
                                                const float* __restrict__ wk,
                                                const float* __restrict__ wv,
                                                const float* __restrict__ wo,
                                                u16* __restrict__ wqb, u16* __restrict__ wkb,
                                                u16* __restrict__ wvb, u16* __restrict__ wob,
                                                float* __restrict__ accZ) {
  int i = blockIdx.x * 256 + threadIdx.x;
  if (i < 589824) {
    const float* src;
    u16* dst;
    int j;
    if (i < 147456) { src = wq; dst = wqb; j = i; }
    else if (i < 294912) { src = wk; dst = wkb; j = i - 147456; }
    else if (i < 442368) { src = wv; dst = wvb; j = i - 294912; }
    else { src = wo; dst = wob; j = i - 442368; }
    float4 v = ((const float4*)src)[j];
    ushort4 o;
    o.x = f2bf(v.x); o.y = f2bf(v.y); o.z = f2bf(v.z); o.w = f2bf(v.w);
    ((ushort4*)dst)[j] = o;
  } else {
    float4 z = {0.0f, 0.0f, 0.0f, 0.0f};
    ((float4*)accZ)[i - 589824] = z;
  }
}

// ---------------------------------------------------------------------------
// GEMM QKV: C = x * W^T, x f32 converted during A-staging (swizzled LDS),
// W bf16 staged via gload_lds with source-XOR swizzle.  128x128, BK=64.
// ---------------------------------------------------------------------------
__global__ __launch_bounds__(256) void r15_gemm_qkv(const float* __restrict__ X,
                                                    const u16* __restrict__ W0,
                                                    const u16* __restrict__ W1,
                                                    const u16* __restrict__ W2,
                                                    u16* __restrict__ C0,
                                                    u16* __restrict__ C1,
                                                    u16* __restrict__ C2) {
  const u16* Wb = (blockIdx.z == 0) ? W0 : (blockIdx.z == 1) ? W1 : W2;
  u16* C = (blockIdx.z == 0) ? C0 : (blockIdx.z == 1) ? C1 : C2;
  __shared__ u16 As[128 * 64];
  __shared__ u16 Bs[128 * 64];
  const int tid = threadIdx.x;
  const int w = tid >> 6, l = tid & 63;
  const int lr = l & 15, lg = l >> 4;
  const int m0 = blockIdx.x * 128, n0 = blockIdx.y * 128;
  const int wr = (w >> 1) * 64, wc = (w & 1) * 64;
  const int arow = tid >> 1;
  const int acol0 = (tid & 1) * 32;
  f32x4 acc[4][4] = {};
  for (int k0 = 0; k0 < 768; k0 += 64) {
    __syncthreads();
    {
      const float* ap = X + (size_t)(m0 + arow) * 768 + k0 + acol0;
#pragma unroll
      for (int q = 0; q < 4; q++) {
        float4 f0 = ((const float4*)ap)[2 * q];
        float4 f1 = ((const float4*)ap)[2 * q + 1];
        int blk = (acol0 >> 3) + q;
        union { ushort4 u4[2]; short8 v; } pk;
        pk.u4[0].x = f2bf(f0.x); pk.u4[0].y = f2bf(f0.y);
        pk.u4[0].z = f2bf(f0.z); pk.u4[0].w = f2bf(f0.w);
        pk.u4[1].x = f2bf(f1.x); pk.u4[1].y = f2bf(f1.y);
        pk.u4[1].z = f2bf(f1.z); pk.u4[1].w = f2bf(f1.w);
        *(short8*)(As + arow * 64 + ((blk ^ (arow & 7)) * 8)) = pk.v;
      }
    }
#pragma unroll
    for (int i = 0; i < 4; i++) {
      int ii = w * 4 + i;
      int row = ii * 8 + (l >> 3);
      int blk = (l & 7) ^ (row & 7);
      lds_ld16(Wb + (size_t)(n0 + row) * 768 + k0 + blk * 8, Bs + ii * 512);
    }
    __syncthreads();
#pragma unroll
    for (int kk = 0; kk < 2; kk++) {
      short8 af[4], bfr[4];
#pragma unroll
      for (int mr = 0; mr < 4; mr++) {
        int r = wr + mr * 16 + lr;
        af[mr] = *(const short8*)(As + r * 64 + (((kk * 4 + lg) ^ (r & 7)) * 8));
      }
#pragma unroll
      for (int nc = 0; nc < 4; nc++) {
        int r = wc + nc * 16 + lr;
        bfr[nc] = *(const short8*)(Bs + r * 64 + (((kk * 4 + lg) ^ (r & 7)) * 8));
      }
#pragma unroll
      for (int mr = 0; mr < 4; mr++)
#pragma unroll
        for (int nc = 0; nc < 4; nc++)
          acc[mr][nc] = __builtin_amdgcn_mfma_f32_16x16x32_bf16(af[mr], bfr[nc], acc[mr][nc], 0, 0, 0);
    }
  }
#pragma unroll
  for (int mr = 0; mr < 4; mr++)
#pragma unroll
    for (int nc = 0; nc < 4; nc++)
#pragma unroll
      for (int ri = 0; ri < 4; ri++) {
        int row = m0 + wr + mr * 16 + lg * 4 + ri;
        int col = n0 + wc + nc * 16 + lr;
        C[(size_t)row * 768 + col] = f2bf(acc[mr][nc][ri]);
      }
}

// ---------------------------------------------------------------------------
// GEMM PROJ: A = accO/accL (fused finalize); W bf16 gload_lds; f32 out.
// ---------------------------------------------------------------------------
__global__ __launch_bounds__(256) void r15_gemm_proj(const float* __restrict__ accO,
                                                     const float* __restrict__ accL,
                                                     const u16* __restrict__ Wb,
                                                     float* __restrict__ C) {
  __shared__ u16 As[128 * 64];
  __shared__ u16 Bs[128 * 64];
  const int tid = threadIdx.x;
  const int w = tid >> 6, l = tid & 63;
  const int lr = l & 15, lg = l >> 4;
  const int m0 = blockIdx.x * 128, n0 = blockIdx.y * 128;
  const int wr = (w >> 1) * 64, wc = (w & 1) * 64;
  const int arow = tid >> 1;
  const int acol0 = (tid & 1) * 32;
  f32x4 acc[4][4] = {};
  for (int k0 = 0; k0 < 768; k0 += 64) {
    __syncthreads();
    {
      const float* ap = accO + (size_t)(m0 + arow) * 768 + k0 + acol0;
      float rl = 1.0f / accL[(m0 + arow) * 6 + (k0 >> 7)];
#pragma unroll
      for (int q = 0; q < 4; q++) {
        float4 f0 = ((const float4*)ap)[2 * q];
        float4 f1 = ((const float4*)ap)[2 * q + 1];
        int blk = (acol0 >> 3) + q;
        union { ushort4 u4[2]; short8 v; } pk;
        pk.u4[0].x = f2bf(f0.x * rl); pk.u4[0].y = f2bf(f0.y * rl);
        pk.u4[0].z = f2bf(f0.z * rl); pk.u4[0].w = f2bf(f0.w * rl);
        pk.u4[1].x = f2bf(f1.x * rl); pk.u4[1].y = f2bf(f1.y * rl);
        pk.u4[1].z = f2bf(f1.z * rl); pk.u4[1].w = f2bf(f1.w * rl);
        *(short8*)(As + arow * 64 + ((blk ^ (arow & 7)) * 8)) = pk.v;
      }
    }
#pragma unroll
    for (int i = 0; i < 4; i++) {
      int ii = w * 4 + i;
      int row = ii * 8 + (l >> 3);
      int blk = (l & 7) ^ (row & 7);
      lds_ld16(Wb + (size_t)(n0 + row) * 768 + k0 + blk * 8, Bs + ii * 512);
    }
    __syncthreads();
#pragma unroll
    for (int kk = 0; kk < 2; kk++) {
      short8 af[4], bfr[4];
#pragma unroll
      for (int mr = 0; mr < 4; mr++) {
        int r = wr + mr * 16 + lr;
        af[mr] = *(const short8*)(As + r * 64 + (((kk * 4 + lg) ^ (r & 7)) * 8));
      }
#pragma unroll
      for (int nc = 0; nc < 4; nc++) {
        int r = wc + nc * 16 + lr;
        bfr[nc] = *(const short8*)(Bs + r * 64 + (((kk * 4 + lg) ^ (r & 7)) * 8));
      }
#pragma unroll
      for (int mr = 0; mr < 4; mr++)
#pragma unroll
        for (int nc = 0; nc < 4; nc++)
          acc[mr][nc] = __builtin_amdgcn_mfma_f32_16x16x32_bf16(af[mr], bfr[nc], acc[mr][nc], 0, 0, 0);
    }
  }
#pragma unroll
  for (int mr = 0; mr < 4; mr++)
#pragma unroll
    for (int nc = 0; nc < 4; nc++)
#pragma unroll
      for (int ri = 0; ri < 4; ri++) {
        int row = m0 + wr + mr * 16 + lg * 4 + ri;
        int col = n0 + wc + nc * 16 + lr;
        C[(size_t)row * 768 + col] = acc[mr][nc][ri];
      }
}

// ---------------------------------------------------------------------------
// Kernel 3: fused RMS-norm + rotary (Q,K) + lambda-mix (V) + out1 copy.
// ---------------------------------------------------------------------------
__global__ __launch_bounds__(256) void r15_normrope(u16* __restrict__ qb,
                                                    u16* __restrict__ kb,
                                                    u16* __restrict__ vb,
                                                    const float* __restrict__ vres,
                                                    const float* __restrict__ lambp,
                                                    const int* __restrict__ pos,
                                                    float* __restrict__ out1) {
  const int wg = blockIdx.x * 4 + (threadIdx.x >> 6);
  const int l = threadIdx.x & 63;
  const int t = wg / 6;
  const int h = wg - t * 6;
  const size_t base = (size_t)t * MODEL + h * 128;
  const float EPS = 1.1920928955078125e-07f;

  float c = 1.0f, sn = 0.0f;
  if (l < 32) {
    float af = exp2f(-10.0f * (float)l * (1.0f / 31.0f));
    float th = (float)pos[t] * af;
    sincosf(th, &sn, &c);
  }
  {
    float a = bf2f(qb[base + l]), b = bf2f(qb[base + 64 + l]);
    float ss = a * a + b * b;
#pragma unroll
    for (int off = 32; off; off >>= 1) ss += __shfl_xor(ss, off);
    float r = rsqrtf(ss * (1.0f / 128.0f) + EPS);
    float an = a * r, bn = b * r;
    qb[base + l] = f2bf(an * c + bn * sn);
    qb[base + 64 + l] = f2bf(bn * c - an * sn);
  }
  {
    float a = bf2f(kb[base + l]), b = bf2f(kb[base + 64 + l]);
    float ss = a * a + b * b;
#pragma unroll
    for (int off = 32; off; off >>= 1) ss += __shfl_xor(ss, off);
    float r = rsqrtf(ss * (1.0f / 128.0f) + EPS);
    float an = a * r, bn = b * r;
    kb[base + l] = f2bf(an * c + bn * sn);
    kb[base + 64 + l] = f2bf(bn * c - an * sn);
  }
  {
    float lm = *lambp;
    float a = bf2f(vb[base + l]), b = bf2f(vb[base + 64 + l]);
    float ra = vres[base + l], rb = vres[base + 64 + l];
    vb[base + l] = f2bf((1.0f - lm) * a + lm * ra);
    vb[base + 64 + l] = f2bf((1.0f - lm) * b + lm * rb);
    out1[base + l] = ra;
    out1[base + 64 + l] = rb;
  }
}

// ---------------------------------------------------------------------------
// Kernel 4: causal flash attention, SPLIT-KV chunk 1024, 2-wave x 32 q-rows,
// 960 blocks longest-first, 32x32 MFMA, in-register P.
// r15: DOUBLE-BUFFERED K (gload_lds -> Ks[nxt]) + async-split V staging
// (global->regs at iter start, regs->vt after post-PV barrier): staging
// latency hides under QK/softmax/PV.  LDS 50KB -> 3 blocks/CU.
// ---------------------------------------------------------------------------
__global__ __launch_bounds__(128, 2) void r15_attn(const u16* __restrict__ Q,
                                                   const u16* __restrict__ K,
                                                   const u16* __restrict__ V,
                                                   float* __restrict__ accO,
                                                   float* __restrict__ accL) {
  const int bx = blockIdx.x;          // 0..959
  const int h = bx / 160;
  const int u = 159 - (bx - h * 160);
  int qt, kc;
  if (u < 16)      { qt = u;                      kc = 0; }
  else if (u < 48) { int v = u - 16; qt = 16 + (v >> 1); kc = v & 1; }
  else if (u < 96) { int v = u - 48; int q3 = v / 3; qt = 32 + q3; kc = v - 3 * q3; }
  else             { int v = u - 96; qt = 48 + (v >> 2); kc = v & 3; }
  const int rowmax = 64 * qt + 63;
  const int c0 = kc << 10;
  const bool islast = (c0 + 1024 > rowmax);
  const int cend = islast ? (rowmax + 1) : (c0 + 1024);
  const int niter = (cend - c0) >> 6;

  const int tid = threadIdx.x;
  const int wv = tid >> 6, l = tid & 63;
  const int lq = l & 31;
  const int hi = l >> 5;

  __shared__ u16 Ks[2][64][128];  // 32 KB double-buffered K
  __shared__ u16 vt[128][72];     // 18 KB V^T

  const int c_ = tid & 31, cc = c_ * 4, g = tid >> 5;
  const int vswz = (c_ & 7) << 3;

  const int qr = qt * 64 + wv * 32;
  const int qrow = qr + lq;

  short8 qf[8];
  {
    const u16* qp = Q + (size_t)qrow * 768 + h * 128 + hi * 8;
#pragma unroll
    for (int s = 0; s < 8; s++) qf[s] = *(const short8*)(qp + s * 16);
  }
  f32x16 oacc[4] = {};
  float lsum = 0.0f;

  // ---- prologue: stage tile 0 (K -> Ks[0], V -> vt) ----
#pragma unroll
  for (int i = 0; i < 8; i++) {
    int rbase = wv * 32 + i * 4;
    int row = rbase + (l >> 4);
    int blk = (l & 15) ^ (row & 7);
    lds_ld16(K + (size_t)(c0 + row) * 768 + h * 128 + blk * 8, &Ks[0][rbase][0]);
  }
#pragma unroll
  for (int it = 0; it < 8; it++) {
    int rloc = 2 * (g + 4 * it);
    ushort4 va = *(const ushort4*)(V + (size_t)(c0 + rloc) * 768 + h * 128 + cc);
    ushort4 vb = *(const ushort4*)(V + (size_t)(c0 + rloc + 1) * 768 + h * 128 + cc);
    int rs = rloc ^ vswz;
    u16 a0[4] = {va.x, va.y, va.z, va.w};
    u16 b0[4] = {vb.x, vb.y, vb.z, vb.w};
#pragma unroll
    for (int q = 0; q < 4; q++) {
      ushort2 t2; t2.x = a0[q]; t2.y = b0[q];
      *(ushort2*)&vt[cc + q][rs] = t2;
    }
  }
  __syncthreads();

  for (int kv = 0; kv < niter; kv++) {
    const int cur = kv & 1;
    const int k0 = c0 + kv * 64;
    const bool pre = (kv + 1 < niter);

    // ---- issue next-tile staging early (K -> Ks[nxt] via gload_lds,
    //      V -> registers); latency hides under QK/softmax/PV ----
    ushort4 va[8], vb2[8];
    if (pre) {
      const int k0n = k0 + 64;
#pragma unroll
      for (int i = 0; i < 8; i++) {
        int rbase = wv * 32 + i * 4;
        int row = rbase + (l >> 4);
        int blk = (l & 15) ^ (row & 7);
        lds_ld16(K + (size_t)(k0n + row) * 768 + h * 128 + blk * 8, &Ks[cur ^ 1][rbase][0]);
      }
#pragma unroll
      for (int it = 0; it < 8; it++) {
        int rloc = 2 * (g + 4 * it);
        va[it] = *(const ushort4*)(V + (size_t)(k0n + rloc) * 768 + h * 128 + cc);
        vb2[it] = *(const ushort4*)(V + (size_t)(k0n + rloc + 1) * 768 + h * 128 + cc);
      }
    }

    // ---- S^T = K Q^T from Ks[cur] ----
    f32x16 sac0 = {}, sac1 = {};
    __builtin_amdgcn_s_setprio(1);
    {
      const int r0_ = lq, r1_ = 32 + lq;
#pragma unroll
      for (int s = 0; s < 8; s++) {
        short8 kf0 = *(const short8*)(&Ks[cur][r0_][((s * 2 + hi) ^ (r0_ & 7)) * 8]);
        sac0 = __builtin_amdgcn_mfma_f32_32x32x16_bf16(kf0, qf[s], sac0, 0, 0, 0);
      }
#pragma unroll
      for (int s = 0; s < 8; s++) {
        short8 kf1 = *(const short8*)(&Ks[cur][r1_][((s * 2 + hi) ^ (r1_ & 7)) * 8]);
        sac1 = __builtin_amdgcn_mfma_f32_32x32x16_bf16(kf1, qf[s], sac1, 0, 0, 0);
      }
    }
    __builtin_amdgcn_s_setprio(0);

    // ---- lane-local softmax ----
    float p[32];
    const bool maskit = islast && (kv == niter - 1);
    if (maskit) {
#pragma unroll
      for (int r = 0; r < 16; r++) {
        int kvg = k0 + (r & 3) + 8 * (r >> 2) + 4 * hi;
        p[r] = (kvg <= qrow) ? exp2f(sac0[r] * SCALE2) : 0.0f;
      }
#pragma unroll
      for (int r = 0; r < 16; r++) {
        int kvg = k0 + 32 + (r & 3) + 8 * (r >> 2) + 4 * hi;
        p[16 + r] = (kvg <= qrow) ? exp2f(sac1[r] * SCALE2) : 0.0f;
      }
    } else {
#pragma unroll
      for (int r = 0; r < 16; r++) p[r] = exp2f(sac0[r] * SCALE2);
#pragma unroll
      for (int r = 0; r < 16; r++) p[16 + r] = exp2f(sac1[r] * SCALE2);
    }
#pragma unroll
    for (int i = 0; i < 32; i++) lsum += p[i];

    // ---- pack P to PV A-frags ----
    union { unsigned int w[4]; short8 v; } pa[4];
#pragma unroll
    for (int s = 0; s < 4; s++) {
      const int b = s * 8;
      unsigned int cA0 = cvtpk_bf16(p[b + 0], p[b + 1]);
      unsigned int cA1 = cvtpk_bf16(p[b + 2], p[b + 3]);
      unsigned int cB0 = cvtpk_bf16(p[b + 4], p[b + 5]);
      unsigned int cB1 = cvtpk_bf16(p[b + 6], p[b + 7]);
      u32x2 s0 = __builtin_amdgcn_permlane32_swap(cA0, cB0, false, false);
      u32x2 s1 = __builtin_amdgcn_permlane32_swap(cA1, cB1, false, false);
      pa[s].w[0] = s0[0]; pa[s].w[1] = s1[0]; pa[s].w[2] = s0[1]; pa[s].w[3] = s1[1];
    }

    // ---- O += P V from vt ----
    __builtin_amdgcn_s_setprio(1);
#pragma unroll
    for (int dt = 0; dt < 4; dt++) {
      const int d = dt * 32 + lq;
      const int dz = ((d >> 2) & 7) << 3;
#pragma unroll
      for (int s = 0; s < 4; s++) {
        short8 vf = *(const short8*)(&vt[d][(s * 16 + hi * 8) ^ dz]);
        oacc[dt] = __builtin_amdgcn_mfma_f32_32x32x16_bf16(pa[s].v, vf, oacc[dt], 0, 0, 0);
      }
    }
    __builtin_amdgcn_s_setprio(0);

    __syncthreads();  // all waves done reading vt & Ks[cur]; vmcnt drained
                      // -> Ks[nxt] staged, va/vb2 loaded

    // ---- write V^T[next] from registers ----
    if (pre) {
#pragma unroll
      for (int it = 0; it < 8; it++) {
        int rloc = 2 * (g + 4 * it);
        int rs = rloc ^ vswz;
        u16 a0[4] = {va[it].x, va[it].y, va[it].z, va[it].w};
        u16 b0[4] = {vb2[it].x, vb2[it].y, vb2[it].z, vb2[it].w};
#pragma unroll
        for (int q = 0; q < 4; q++) {
          ushort2 t2; t2.x = a0[q]; t2.y = b0[q];
          *(ushort2*)&vt[cc + q][rs] = t2;
        }
      }
    }
    __syncthreads();  // vt(next) visible to all waves
  }

  // ---- accumulate partials (f32 hardware atomics) ----
#pragma unroll
  for (int dt = 0; dt < 4; dt++) {
    const int d = dt * 32 + lq;
#pragma unroll
    for (int r = 0; r < 16; r++) {
      int qrw = qr + (r & 3) + 8 * (r >> 2) + 4 * hi;
      unsafeAtomicAdd(&accO[(size_t)qrw * 768 + h * 128 + d], oacc[dt][r]);
    }
  }
  unsafeAtomicAdd(&accL[qrow * 6 + h], lsum);
}

// ---------------------------------------------------------------------------
// d_out FLOAT32: out0 = y@Wo^T [3145728 f32], out1 = v_residual [3145728].
// Workspace (36.3 MB): wqb/wkb/wvb/wob bf16, qb/kb/vb, accO+accL.
// ---------------------------------------------------------------------------
extern "C" void kernel_launch(void* const* d_in, const int* in_sizes, int n_in,
                              void* d_out, int out_size, void* d_ws, size_t ws_size,
                              hipStream_t stream) {
  const float* x = (const float*)d_in[0];
  const float* vres = (const float*)d_in[1];
  const float* Wq = (const float*)d_in[2];
  const float* Wk = (const float*)d_in[3];
  const float* Wv = (const float*)d_in[4];
  const float* Wo = (const float*)d_in[5];
  const float* lamb = (const float*)d_in[6];
  const int* pos = (const int*)d_in[7];
  float* out = (float*)d_out;

  u16* wqb = (u16*)d_ws;
  u16* wkb = wqb + 589824;
  u16* wvb = wkb + 589824;
  u16* wob = wvb + 589824;
  u16* qb = wob + 589824;
  u16* kb = qb + 3145728;
  u16* vb = kb + 3145728;
  float* accO = (float*)(vb + 3145728);
  float* accL = accO + 3145728;
  float* out1 = out + 3145728;

  r15_prep<<<5400, 256, 0, stream>>>(Wq, Wk, Wv, Wo, wqb, wkb, wvb, wob, accO);
  r15_gemm_qkv<<<dim3(32, 6, 3), 256, 0, stream>>>(x, wqb, wkb, wvb, qb, kb, vb);
  r15_normrope<<<6144, 256, 0, stream>>>(qb, kb, vb, vres, lamb, pos, out1);
  r15_attn<<<960, 128, 0, stream>>>(qb, kb, vb, accO, accL);
  r15_gemm_proj<<<dim3(32, 6), 256, 0, stream>>>(accO, accL, wob, out);
}

// Round 16
// 161.497 us; speedup vs baseline: 1.4508x; 1.4508x over previous
//
#include <hip/hip_runtime.h>
#include <hip/hip_bf16.h>

typedef unsigned short u16;
typedef __attribute__((ext_vector_type(8))) short short8;
typedef __attribute__((ext_vector_type(4))) float f32x4;
typedef __attribute__((ext_vector_type(16))) float f32x16;
typedef __attribute__((ext_vector_type(2))) unsigned int u32x2;

#define MODEL 768
// 1/sqrt(128) * log2(e): exp(s/sqrt(128)) == exp2(s * SCALE2)
#define SCALE2 0.1275174137f

__device__ __forceinline__ float bf2f(u16 u) {
  unsigned int x = ((unsigned int)u) << 16;
  return __uint_as_float(x);
}
__device__ __forceinline__ u16 f2bf(float f) {
  unsigned int x = __float_as_uint(f);
  unsigned int r = (x + 0x7FFFu + ((x >> 16) & 1u)) >> 16;
  return (u16)r;
}
__device__ __forceinline__ void lds_ld16(const u16* g, u16* l) {
  __builtin_amdgcn_global_load_lds((const __attribute__((address_space(1))) void*)g,
                                   (__attribute__((address_space(3))) void*)l, 16, 0, 0);
}
__device__ __forceinline__ unsigned int cvtpk_bf16(float lo, float hi_) {
  unsigned int r;
  asm("v_cvt_pk_bf16_f32 %0, %1, %2" : "=v"(r) : "v"(lo), "v"(hi_));
  return r;
}

// ---------------------------------------------------------------------------
// Kernel 1: x f32 -> bf16 (786432 float4 units) AND zero accO/accL
// (792576 float4 units).  Grid 6168 x 256.
// ---------------------------------------------------------------------------
__global__ __launch_bounds__(256) void r16_cvt_x(const float* __restrict__ x,
                                                 u16* __restrict__ xb,
                                                 float* __restrict__ accZ) {
  int i = blockIdx.x * 256 + threadIdx.x;
  if (i < 786432) {
    float4 v = ((const float4*)x)[i];
    ushort4 o;
    o.x = f2bf(v.x); o.y = f2bf(v.y); o.z = f2bf(v.z); o.w = f2bf(v.w);
    ((ushort4*)xb)[i] = o;
  } else if (i < 786432 + 792576) {
    float4 z = {0.0f, 0.0f, 0.0f, 0.0f};
    ((float4*)accZ)[i - 786432] = z;
  }
}

// ---------------------------------------------------------------------------
// GEMM QKV (r12-proven): C = A_bf16 * W_f32^T.  128x128 tile, BK=32,
// 4 waves, 4x4 16x16x32 bf16 MFMA.  A via gload_lds; W converted f32->bf16
// during staging.
// ---------------------------------------------------------------------------
__global__ __launch_bounds__(256) void r16_gemm_qkv(const u16* __restrict__ A,
                                                    const float* __restrict__ W0,
                                                    const float* __restrict__ W1,
                                                    const float* __restrict__ W2,
                                                    u16* __restrict__ C0,
                                                    u16* __restrict__ C1,
                                                    u16* __restrict__ C2) {
  const float* W = (blockIdx.z == 0) ? W0 : (blockIdx.z == 1) ? W1 : W2;
  u16* C = (blockIdx.z == 0) ? C0 : (blockIdx.z == 1) ? C1 : C2;
  __shared__ u16 As[128 * 32];
  __shared__ u16 Bs[128 * 32];
  const int tid = threadIdx.x;
  const int w = tid >> 6, l = tid & 63;
  const int lr = l & 15, lg = l >> 4;
  const int m0 = blockIdx.x * 128, n0 = blockIdx.y * 128;
  const int wr = (w >> 1) * 64, wc = (w & 1) * 64;
  const int sr = w * 32 + (l >> 2);
  const int sc = (l & 3) * 8;
  const int qrow = tid >> 1;
  const int qoff = (tid & 1) * 16;
  f32x4 acc[4][4] = {};
  for (int k0 = 0; k0 < 768; k0 += 32) {
    __syncthreads();
    lds_ld16(A + (size_t)(m0 + sr) * 768 + k0 + sc, As + (w * 2 + 0) * 512);
    lds_ld16(A + (size_t)(m0 + sr + 16) * 768 + k0 + sc, As + (w * 2 + 1) * 512);
    {
      const float* wp = W + (size_t)(n0 + qrow) * 768 + k0 + qoff;
      u16* bp = Bs + qrow * 32 + qoff;
#pragma unroll
      for (int q = 0; q < 4; q++) {
        float4 f = ((const float4*)wp)[q];
        ushort4 b;
        b.x = f2bf(f.x); b.y = f2bf(f.y); b.z = f2bf(f.z); b.w = f2bf(f.w);
        *(ushort4*)(bp + q * 4) = b;
      }
    }
    __syncthreads();
    short8 af[4], bfr[4];
#pragma unroll
    for (int mr = 0; mr < 4; mr++) af[mr] = *(const short8*)(As + (wr + mr * 16 + lr) * 32 + lg * 8);
#pragma unroll
    for (int nc = 0; nc < 4; nc++) bfr[nc] = *(const short8*)(Bs + (wc + nc * 16 + lr) * 32 + lg * 8);
#pragma unroll
    for (int mr = 0; mr < 4; mr++)
#pragma unroll
      for (int nc = 0; nc < 4; nc++)
        acc[mr][nc] = __builtin_amdgcn_mfma_f32_16x16x32_bf16(af[mr], bfr[nc], acc[mr][nc], 0, 0, 0);
  }
#pragma unroll
  for (int mr = 0; mr < 4; mr++)
#pragma unroll
    for (int nc = 0; nc < 4; nc++)
#pragma unroll
      for (int ri = 0; ri < 4; ri++) {
        int row = m0 + wr + mr * 16 + lg * 4 + ri;
        int col = n0 + wc + nc * 16 + lr;
        C[(size_t)row * 768 + col] = f2bf(acc[mr][nc][ri]);
      }
}

// PROJ (r12-proven): A = accO/accL (fused finalize), output f32 to d_out.
__global__ __launch_bounds__(256) void r16_gemm_proj(const float* __restrict__ accO,
                                                     const float* __restrict__ accL,
                                                     const float* __restrict__ W,
                                                     float* __restrict__ C) {
  __shared__ u16 As[128 * 32];
  __shared__ u16 Bs[128 * 32];
  const int tid = threadIdx.x;
  const int w = tid >> 6, l = tid & 63;
  const int lr = l & 15, lg = l >> 4;
  const int m0 = blockIdx.x * 128, n0 = blockIdx.y * 128;
  const int wr = (w >> 1) * 64, wc = (w & 1) * 64;
  const int qrow = tid >> 1;
  const int qoff = (tid & 1) * 16;
  f32x4 acc[4][4] = {};
  for (int k0 = 0; k0 < 768; k0 += 32) {
    __syncthreads();
    {
      const float* ap = accO + (size_t)(m0 + qrow) * 768 + k0 + qoff;
      float rl = 1.0f / accL[(m0 + qrow) * 6 + (k0 >> 7)];
      u16* dp = As + qrow * 32 + qoff;
#pragma unroll
      for (int q = 0; q < 4; q++) {
        float4 f = ((const float4*)ap)[q];
        ushort4 b;
        b.x = f2bf(f.x * rl); b.y = f2bf(f.y * rl);
        b.z = f2bf(f.z * rl); b.w = f2bf(f.w * rl);
        *(ushort4*)(dp + q * 4) = b;
      }
      const float* wp = W + (size_t)(n0 + qrow) * 768 + k0 + qoff;
      u16* bp = Bs + qrow * 32 + qoff;
#pragma unroll
      for (int q = 0; q < 4; q++) {
        float4 f = ((const float4*)wp)[q];
        ushort4 b;
        b.x = f2bf(f.x); b.y = f2bf(f.y); b.z = f2bf(f.z); b.w = f2bf(f.w);
        *(ushort4*)(bp + q * 4) = b;
      }
    }
    __syncthreads();
    short8 af[4], bfr[4];
#pragma unroll
    for (int mr = 0; mr < 4; mr++) af[mr] = *(const short8*)(As + (wr + mr * 16 + lr) * 32 + lg * 8);
#pragma unroll
    for (int nc = 0; nc < 4; nc++) bfr[nc] = *(const short8*)(Bs + (wc + nc * 16 + lr) * 32 + lg * 8);
#pragma unroll
    for (int mr = 0; mr < 4; mr++)
#pragma unroll
      for (int nc = 0; nc < 4; nc++)
        acc[mr][nc] = __builtin_amdgcn_mfma_f32_16x16x32_bf16(af[mr], bfr[nc], acc[mr][nc], 0, 0, 0);
  }
#pragma unroll
  for (int mr = 0; mr < 4; mr++)
#pragma unroll
    for (int nc = 0; nc < 4; nc++)
#pragma unroll
      for (int ri = 0; ri < 4; ri++) {
        int row = m0 + wr + mr * 16 + lg * 4 + ri;
        int col = n0 + wc + nc * 16 + lr;
        C[(size_t)row * 768 + col] = acc[mr][nc][ri];
      }
}

// ---------------------------------------------------------------------------
// Kernel 3: fused RMS-norm + rotary (Q,K) + lambda-mix (V) + out1 copy.
// ---------------------------------------------------------------------------
__global__ __launch_bounds__(256) void r16_normrope(u16* __restrict__ qb,
                                                    u16* __restrict__ kb,
                                                    u16* __restrict__ vb,
                                                    const float* __restrict__ vres,
                                                    const float* __restrict__ lambp,
                                                    const int* __restrict__ pos,
                                                    float* __restrict__ out1) {
  const int wg = blockIdx.x * 4 + (threadIdx.x >> 6);
  const int l = threadIdx.x & 63;
  const int t = wg / 6;
  const int h = wg - t * 6;
  const size_t base = (size_t)t * MODEL + h * 128;
  const float EPS = 1.1920928955078125e-07f;

  float c = 1.0f, sn = 0.0f;
  if (l < 32) {
    float af = exp2f(-10.0f * (float)l * (1.0f / 31.0f));
    float th = (float)pos[t] * af;
    sincosf(th, &sn, &c);
  }
  {
    float a = bf2f(qb[base + l]), b = bf2f(qb[base + 64 + l]);
    float ss = a * a + b * b;
#pragma unroll
    for (int off = 32; off; off >>= 1) ss += __shfl_xor(ss, off);
    float r = rsqrtf(ss * (1.0f / 128.0f) + EPS);
    float an = a * r, bn = b * r;
    qb[base + l] = f2bf(an * c + bn * sn);
    qb[base + 64 + l] = f2bf(bn * c - an * sn);
  }
  {
    float a = bf2f(kb[base + l]), b = bf2f(kb[base + 64 + l]);
    float ss = a * a + b * b;
#pragma unroll
    for (int off = 32; off; off >>= 1) ss += __shfl_xor(ss, off);
    float r = rsqrtf(ss * (1.0f / 128.0f) + EPS);
    float an = a * r, bn = b * r;
    kb[base + l] = f2bf(an * c + bn * sn);
    kb[base + 64 + l] = f2bf(bn * c - an * sn);
  }
  {
    float lm = *lambp;
    float a = bf2f(vb[base + l]), b = bf2f(vb[base + 64 + l]);
    float ra = vres[base + l], rb = vres[base + 64 + l];
    vb[base + l] = f2bf((1.0f - lm) * a + lm * ra);
    vb[base + 64 + l] = f2bf((1.0f - lm) * b + lm * rb);
    out1[base + l] = ra;            // output 1 = v_residual verbatim
    out1[base + 64 + l] = rb;
  }
}

// ---------------------------------------------------------------------------
// Kernel 4: causal flash attention (r12-exact config, 3x reproduced at
// ~73 us): SPLIT-KV chunk 1024, 2-wave blocks x 32 q-rows, 960 blocks
// longest-first, 32x32 MFMA swapped QK^T, in-register P via cvt_pk +
// permlane32_swap, static-max softmax, f32 hardware atomics.
// Single-buffered LDS 34KB -> 4 blocks/CU; 1 barrier pair per iter.
// ---------------------------------------------------------------------------
__global__ __launch_bounds__(128, 2) void r16_attn(const u16* __restrict__ Q,
                                                   const u16* __restrict__ K,
                                                   const u16* __restrict__ V,
                                                   float* __restrict__ accO,
                                                   float* __restrict__ accL) {
  const int bx = blockIdx.x;          // 0..959
  const int h = bx / 160;
  const int u = 159 - (bx - h * 160);
  int qt, kc;
  if (u < 16)      { qt = u;                      kc = 0; }
  else if (u < 48) { int v = u - 16; qt = 16 + (v >> 1); kc = v & 1; }
  else if (u < 96) { int v = u - 48; int q3 = v / 3; qt = 32 + q3; kc = v - 3 * q3; }
  else             { int v = u - 96; qt = 48 + (v >> 2); kc = v & 3; }
  const int rowmax = 64 * qt + 63;
  const int c0 = kc << 10;
  const bool islast = (c0 + 1024 > rowmax);
  const int cend = islast ? (rowmax + 1) : (c0 + 1024);
  const int niter = (cend - c0) >> 6;

  const int tid = threadIdx.x;
  const int wv = tid >> 6, l = tid & 63;
  const int lq = l & 31;
  const int hi = l >> 5;

  __shared__ u16 Ks[64][128];
  __shared__ u16 vt[128][72];

  const int c_ = tid & 31, cc = c_ * 4, g = tid >> 5;
  const int vswz = (c_ & 7) << 3;

  const int qr = qt * 64 + wv * 32;
  const int qrow = qr + lq;

  short8 qf[8];
  {
    const u16* qp = Q + (size_t)qrow * 768 + h * 128 + hi * 8;
#pragma unroll
    for (int s = 0; s < 8; s++) qf[s] = *(const short8*)(qp + s * 16);
  }
  f32x16 oacc[4] = {};
  float lsum = 0.0f;

  for (int kv = 0; kv < niter; kv++) {
    const int k0 = c0 + kv * 64;

#pragma unroll
    for (int i = 0; i < 8; i++) {
      int rbase = wv * 32 + i * 4;
      int row = rbase + (l >> 4);
      int blk = (l & 15) ^ (row & 7);
      lds_ld16(K + (size_t)(k0 + row) * 768 + h * 128 + blk * 8, &Ks[rbase][0]);
    }
#pragma unroll
    for (int it = 0; it < 8; it++) {
      int rloc = 2 * (g + 4 * it);
      ushort4 va = *(const ushort4*)(V + (size_t)(k0 + rloc) * 768 + h * 128 + cc);
      ushort4 vb = *(const ushort4*)(V + (size_t)(k0 + rloc + 1) * 768 + h * 128 + cc);
      int rs = rloc ^ vswz;
      u16 a0[4] = {va.x, va.y, va.z, va.w};
      u16 b0[4] = {vb.x, vb.y, vb.z, vb.w};
#pragma unroll
      for (int q = 0; q < 4; q++) {
        ushort2 t2; t2.x = a0[q]; t2.y = b0[q];
        *(ushort2*)&vt[cc + q][rs] = t2;
      }
    }
    __syncthreads();

    f32x16 sac0 = {}, sac1 = {};
    __builtin_amdgcn_s_setprio(1);
    {
      const int r0_ = lq, r1_ = 32 + lq;
#pragma unroll
      for (int s = 0; s < 8; s++) {
        short8 kf0 = *(const short8*)(&Ks[r0_][((s * 2 + hi) ^ (r0_ & 7)) * 8]);
        sac0 = __builtin_amdgcn_mfma_f32_32x32x16_bf16(kf0, qf[s], sac0, 0, 0, 0);
      }
#pragma unroll
      for (int s = 0; s < 8; s++) {
        short8 kf1 = *(const short8*)(&Ks[r1_][((s * 2 + hi) ^ (r1_ & 7)) * 8]);
        sac1 = __builtin_amdgcn_mfma_f32_32x32x16_bf16(kf1, qf[s], sac1, 0, 0, 0);
      }
    }
    __builtin_amdgcn_s_setprio(0);

    float p[32];
    const bool maskit = islast && (kv == niter - 1);
    if (maskit) {
#pragma unroll
      for (int r = 0; r < 16; r++) {
        int kvg = k0 + (r & 3) + 8 * (r >> 2) + 4 * hi;
        p[r] = (kvg <= qrow) ? exp2f(sac0[r] * SCALE2) : 0.0f;
      }
#pragma unroll
      for (int r = 0; r < 16; r++) {
        int kvg = k0 + 32 + (r & 3) + 8 * (r >> 2) + 4 * hi;
        p[16 + r] = (kvg <= qrow) ? exp2f(sac1[r] * SCALE2) : 0.0f;
      }
    } else {
#pragma unroll
      for (int r = 0; r < 16; r++) p[r] = exp2f(sac0[r] * SCALE2);
#pragma unroll
      for (int r = 0; r < 16; r++) p[16 + r] = exp2f(sac1[r] * SCALE2);
    }
#pragma unroll
    for (int i = 0; i < 32; i++) lsum += p[i];

    union { unsigned int w[4]; short8 v; } pa[4];
#pragma unroll
    for (int s = 0; s < 4; s++) {
      const int b = s * 8;
      unsigned int cA0 = cvtpk_bf16(p[b + 0], p[b + 1]);
      unsigned int cA1 = cvtpk_bf16(p[b + 2], p[b + 3]);
      unsigned int cB0 = cvtpk_bf16(p[b + 4], p[b + 5]);
      unsigned int cB1 = cvtpk_bf16(p[b + 6], p[b + 7]);
      u32x2 s0 = __builtin_amdgcn_permlane32_swap(cA0, cB0, false, false);
      u32x2 s1 = __builtin_amdgcn_permlane32_swap(cA1, cB1, false, false);
      pa[s].w[0] = s0[0]; pa[s].w[1] = s1[0]; pa[s].w[2] = s0[1]; pa[s].w[3] = s1[1];
    }

    __builtin_amdgcn_s_setprio(1);
#pragma unroll
    for (int dt = 0; dt < 4; dt++) {
      const int d = dt * 32 + lq;
      const int dz = ((d >> 2) & 7) << 3;
#pragma unroll
      for (int s = 0; s < 4; s++) {
        short8 vf = *(const short8*)(&vt[d][(s * 16 + hi * 8) ^ dz]);
        oacc[dt] = __builtin_amdgcn_mfma_f32_32x32x16_bf16(pa[s].v, vf, oacc[dt], 0, 0, 0);
      }
    }
    __builtin_amdgcn_s_setprio(0);
    __syncthreads();
  }

#pragma unroll
  for (int dt = 0; dt < 4; dt++) {
    const int d = dt * 32 + lq;
#pragma unroll
    for (int r = 0; r < 16; r++) {
      int qrw = qr + (r & 3) + 8 * (r >> 2) + 4 * hi;
      unsafeAtomicAdd(&accO[(size_t)qrw * 768 + h * 128 + d], oacc[dt][r]);
    }
  }
  unsafeAtomicAdd(&accL[qrow * 6 + h], lsum);
}

// ---------------------------------------------------------------------------
// d_out FLOAT32: out0 = y@Wo^T [3145728 f32], out1 = v_residual [3145728].
// Workspace (r12 layout, 37.9 MB): xb@0, qb, kb, vb (u16), accO+accL (f32).
// ---------------------------------------------------------------------------
extern "C" void kernel_launch(void* const* d_in, const int* in_sizes, int n_in,
                              void* d_out, int out_size, void* d_ws, size_t ws_size,
                              hipStream_t stream) {
  const float* x = (const float*)d_in[0];
  const float* vres = (const float*)d_in[1];
  const float* Wq = (const float*)d_in[2];
  const float* Wk = (const float*)d_in[3];
  const float* Wv = (const float*)d_in[4];
  const float* Wo = (const float*)d_in[5];
  const float* lamb = (const float*)d_in[6];
  const int* pos = (const int*)d_in[7];
  float* out = (float*)d_out;

  u16* xb = (u16*)d_ws;
  u16* qb = xb + 3145728;
  u16* kb = qb + 3145728;
  u16* vb = kb + 3145728;
  float* accO = (float*)((char*)d_ws + 25165824);
  float* accL = accO + 3145728;
  float* out1 = out + 3145728;

  r16_cvt_x<<<6168, 256, 0, stream>>>(x, xb, accO);
  r16_gemm_qkv<<<dim3(32, 6, 3), 256, 0, stream>>>(xb, Wq, Wk, Wv, qb, kb, vb);
  r16_normrope<<<6144, 256, 0, stream>>>(qb, kb, vb, vres, lamb, pos, out1);
  r16_attn<<<960, 128, 0, stream>>>(qb, kb, vb, accO, accL);
  r16_gemm_proj<<<dim3(32, 6), 256, 0, stream>>>(accO, accL, Wo, out);
}